// Round 14
// baseline (438.230 us; speedup 1.0000x reference)
//
#include <hip/hip_runtime.h>

#define Dh 128
#define NN 50000
#define EE 800000
#define RR 8
#define BB 4
#define LL 2
#define NW 1152           // 8 relation blocks + self block, wide-GEMM N
#define TROW 576          // NW/2 uints per T row
#define BN_EPS 1e-3f
#define NR (NN * RR)
#define NBLK 196          // (NN+255)/256

// prep_all block-range boundaries
#define PB_WF0T   576                       // NW*Dh/256
#define PB_WCAT1  (PB_WF0T + 576)
#define PB_BF0    (PB_WCAT1 + 5)            // ceil(NW/256)
#define PB_NF     (PB_BF0 + 3125)           // NN*Dh/8/256
#define PB_ZERO   (PB_NF + 1563)            // ceil(NR/256)

typedef __attribute__((ext_vector_type(8))) short bf16x8;
typedef __attribute__((ext_vector_type(4))) float f32x4;

__device__ inline unsigned short f2bf(float x) {
    unsigned u = __float_as_uint(x);
    unsigned r = (u + 0x7fffu + ((u >> 16) & 1u)) >> 16;
    return (unsigned short)r;
}

// wideT0[f][c] inline: f<1024 -> sum_b w_coe[0,r,b]*bases[0,b,c,f&127], else self_loop[0,c,f&127]
__device__ inline float wide0_fc(
    const float* __restrict__ bases, const float* __restrict__ w_coe,
    const float* __restrict__ self_loop, int f, int c)
{
    int fl = f & 127;
    if (f < RR * Dh) {
        int r = f >> 7;
        float acc = 0.f;
        #pragma unroll
        for (int b = 0; b < BB; b++)
            acc += w_coe[r * BB + b] * bases[((b * Dh) + c) * Dh + fl];
        return acc;
    }
    return self_loop[c * Dh + fl];
}

// ---------------------------------------------------------------------------
// prep_all (r14): one launch replaces build_wideT/build_wembT/fold_w/fold_b/
// convert_nf/memset(counts) — 6 dispatches -> 1 (launch-gap tail was ~147us).
//   [0,576):       WF0T[f][d]  = bf16( sum_c wide0(f,c) * W_emb[d][c] )
//   [576,1152):    wcatT1[f][c]= bf16( wide1(f,c) )   (layer-1 B operand)
//   [1152,1157):   bf0[f]      = sum_c wide0(f,c) * b_emb[c]
//   [1157,4282):   nf_bf       = bf16(node_feat)  (8 elems/thread)
//   [4282,5845):   counts      = 0
// ---------------------------------------------------------------------------
__global__ __launch_bounds__(256) void prep_all_kernel(
    const float* __restrict__ bases, const float* __restrict__ w_coe,
    const float* __restrict__ self_loop, const float* __restrict__ W_emb,
    const float* __restrict__ b_emb, const float* __restrict__ nf,
    unsigned short* __restrict__ WF0T, unsigned short* __restrict__ wcatT1,
    float* __restrict__ bf0, unsigned short* __restrict__ nf_bf,
    int* __restrict__ counts)
{
    int bid = blockIdx.x;
    int t = threadIdx.x;
    if (bid < PB_WF0T) {
        int idx = bid * 256 + t;               // [0, NW*Dh)
        int f = idx >> 7;
        int d = idx & 127;
        float acc = 0.f;
        if (f < RR * Dh) {
            int r = f >> 7, fl = f & 127;
            float c0 = w_coe[r * BB + 0], c1 = w_coe[r * BB + 1];
            float c2 = w_coe[r * BB + 2], c3 = w_coe[r * BB + 3];
            for (int c = 0; c < Dh; c++) {
                float w = c0 * bases[c * Dh + fl]
                        + c1 * bases[(Dh * Dh) + c * Dh + fl]
                        + c2 * bases[(2 * Dh * Dh) + c * Dh + fl]
                        + c3 * bases[(3 * Dh * Dh) + c * Dh + fl];
                acc += w * W_emb[d * Dh + c];
            }
        } else {
            int fl = f & 127;
            for (int c = 0; c < Dh; c++)
                acc += self_loop[c * Dh + fl] * W_emb[d * Dh + c];
        }
        WF0T[(size_t)f * Dh + d] = f2bf(acc);
    } else if (bid < PB_WCAT1) {
        int idx = (bid - PB_WF0T) * 256 + t;   // [0, NW*Dh)
        int f = idx >> 7;
        int c = idx & 127;
        float val;
        int fl = f & 127;
        if (f < RR * Dh) {
            int r = f >> 7;
            float acc = 0.f;
            #pragma unroll
            for (int b = 0; b < BB; b++)
                acc += w_coe[(RR + r) * BB + b]
                     * bases[(((BB + b) * Dh) + c) * Dh + fl];
            val = acc;
        } else {
            val = self_loop[(Dh + c) * Dh + fl];
        }
        wcatT1[(size_t)f * Dh + c] = f2bf(val);
    } else if (bid < PB_BF0) {
        int f = (bid - PB_WCAT1) * 256 + t;
        if (f < NW) {
            float acc = 0.f;
            for (int c = 0; c < Dh; c++)
                acc += wide0_fc(bases, w_coe, self_loop, f, c) * b_emb[c];
            bf0[f] = acc;
        }
    } else if (bid < PB_NF) {
        int idx = (bid - PB_BF0) * 256 + t;    // exactly NN*Dh/8
        size_t base = (size_t)idx * 8;
        float4 v0 = *(const float4*)&nf[base];
        float4 v1 = *(const float4*)&nf[base + 4];
        unsigned short o[8] = { f2bf(v0.x), f2bf(v0.y), f2bf(v0.z), f2bf(v0.w),
                                f2bf(v1.x), f2bf(v1.y), f2bf(v1.z), f2bf(v1.w) };
        *(uint4*)&nf_bf[base] = *(uint4*)o;
    } else {
        int idx = (bid - PB_NF) * 256 + t;
        if (idx < NR) counts[idx] = 0;
    }
}

// ---------------------------------------------------------------------------
// Wide MFMA GEMM: T[M x 1152](bf16) = A[M x 128](bf16) @ Wt[1152 x 128]^T (+bias).
// K=128 single pass, 128x64 tile, grid (18 cols fast, 391 rows) for A L2 reuse.
// ---------------------------------------------------------------------------
__global__ __launch_bounds__(256) void gemm_wide_kernel(
    const unsigned short* __restrict__ A,
    const unsigned short* __restrict__ Wt,
    const float* __restrict__ bias,          // may be null
    unsigned short* __restrict__ T, int M)
{
    __shared__ unsigned short a_s[128][136];   // 34 KB
    __shared__ unsigned short b_s[64][136];    // 17 KB
    int t    = threadIdx.x;
    int wave = t >> 6;
    int lane = t & 63;
    int wr   = wave * 32;            // each wave: 32 rows x all 64 cols
    int row0 = blockIdx.y * 128;     // y = row tile (slow)
    int col0 = blockIdx.x * 64;      // x = col tile (fast)
    int n16  = lane & 15;
    int quad = lane >> 4;

    // stage A: thread t -> row t>>1, half t&1 (64 bf16 = 8 uint4)
    {
        int srow = t >> 1, shalf = t & 1;
        int gr = row0 + srow;
        const uint4* gp = (const uint4*)&A[(size_t)gr * Dh + shalf * 64];
        #pragma unroll
        for (int i = 0; i < 8; i++) {
            uint4 av = make_uint4(0u, 0u, 0u, 0u);
            if (gr < M) av = gp[i];
            *(uint4*)&a_s[srow][shalf * 64 + i * 8] = av;
        }
    }
    // stage B: thread t -> row t>>2, quarter t&3 (32 bf16 = 4 uint4)
    {
        int srow = t >> 2, sq = t & 3;
        const uint4* wp = (const uint4*)&Wt[(size_t)(col0 + srow) * Dh + sq * 32];
        #pragma unroll
        for (int i = 0; i < 4; i++)
            *(uint4*)&b_s[srow][sq * 32 + i * 8] = wp[i];
    }
    __syncthreads();

    f32x4 acc[2][4];
    #pragma unroll
    for (int i = 0; i < 2; i++)
        #pragma unroll
        for (int j = 0; j < 4; j++)
            acc[i][j] = (f32x4){0.f, 0.f, 0.f, 0.f};

    #pragma unroll
    for (int kc = 0; kc < 4; kc++) {
        bf16x8 af[2], bf[4];
        #pragma unroll
        for (int i = 0; i < 2; i++)
            af[i] = *(const bf16x8*)&a_s[wr + i * 16 + n16][kc * 32 + quad * 8];
        #pragma unroll
        for (int j = 0; j < 4; j++)
            bf[j] = *(const bf16x8*)&b_s[j * 16 + n16][kc * 32 + quad * 8];
        #pragma unroll
        for (int i = 0; i < 2; i++)
            #pragma unroll
            for (int j = 0; j < 4; j++)
                acc[i][j] = __builtin_amdgcn_mfma_f32_16x16x32_bf16(
                    af[i], bf[j], acc[i][j], 0, 0, 0);
    }

    float bj[4];
    #pragma unroll
    for (int j = 0; j < 4; j++)
        bj[j] = bias ? bias[col0 + j * 16 + n16] : 0.f;

    #pragma unroll
    for (int i = 0; i < 2; i++) {
        #pragma unroll
        for (int v = 0; v < 4; v++) {
            int gr = row0 + wr + i * 16 + quad * 4 + v;
            if (gr < M) {
                #pragma unroll
                for (int j = 0; j < 4; j++)
                    T[(size_t)gr * NW + col0 + j * 16 + n16] =
                        f2bf(acc[i][j][v] + bj[j]);
            }
        }
    }
}

// ---------------------------------------------------------------------------
// Per-(node,relation) histogram
// ---------------------------------------------------------------------------
__global__ __launch_bounds__(256) void count_kernel(
    const int* __restrict__ dst, const int* __restrict__ etype,
    int* __restrict__ counts)
{
    int e = blockIdx.x * 256 + threadIdx.x;
    if (e < EE) atomicAdd(&counts[dst[e] * RR + etype[e]], 1);
}

// ---------------------------------------------------------------------------
// scan1 (r14: norm_deg folded in): reads counts[n*8..], computes deg + norm
// inline, block-local exclusive scan of deg, emits block sum.
// ---------------------------------------------------------------------------
__global__ __launch_bounds__(256) void scan1_kernel(
    const int* __restrict__ counts, float* __restrict__ node_norm,
    int* __restrict__ row_ptr, int* __restrict__ bsum)
{
    __shared__ int s[256];
    int t = threadIdx.x;
    int n = blockIdx.x * 256 + t;
    int d = 0;
    if (n < NN) {
        float norm = 0.f;
        #pragma unroll
        for (int r = 0; r < RR; r++) {
            int c = counts[n * RR + r];
            d += c;
            if (c > 0) norm = 1.0f / (float)c;   // later r overwrites (ref sem.)
        }
        node_norm[n] = norm;
    }
    s[t] = d;
    __syncthreads();
    #pragma unroll
    for (int off = 1; off < 256; off <<= 1) {
        int v = (t >= off) ? s[t - off] : 0;
        __syncthreads();
        s[t] += v;
        __syncthreads();
    }
    if (n < NN) row_ptr[n] = s[t] - d;
    if (t == 255) bsum[blockIdx.x] = s[255];
}

__global__ __launch_bounds__(256) void scan2_kernel(
    const int* __restrict__ bsum, int* __restrict__ boffset)
{
    __shared__ int s[256];
    int t = threadIdx.x;
    int d = (t < NBLK) ? bsum[t] : 0;
    s[t] = d;
    __syncthreads();
    #pragma unroll
    for (int off = 1; off < 256; off <<= 1) {
        int v = (t >= off) ? s[t - off] : 0;
        __syncthreads();
        s[t] += v;
        __syncthreads();
    }
    if (t <= NBLK) boffset[t] = s[t] - d;
}

__global__ __launch_bounds__(256) void scan3_kernel(
    int* __restrict__ row_ptr, int* __restrict__ cursor,
    const int* __restrict__ boffset)
{
    int t = threadIdx.x;
    int n = blockIdx.x * 256 + t;
    if (n < NN) {
        int v = row_ptr[n] + boffset[blockIdx.x];
        row_ptr[n] = v;
        cursor[n]  = v;
    }
    if (blockIdx.x == 0 && t == 0) row_ptr[NN] = EE;
}

// ---------------------------------------------------------------------------
// Fill per-node CSR: packed edge = src | (etype<<16)
// ---------------------------------------------------------------------------
__global__ __launch_bounds__(256) void fill_kernel(
    const int* __restrict__ src, const int* __restrict__ dst,
    const int* __restrict__ etype, int* __restrict__ cursor,
    unsigned* __restrict__ packed)
{
    int e = blockIdx.x * 256 + threadIdx.x;
    if (e < EE) {
        int pos = atomicAdd(&cursor[dst[e]], 1);
        packed[pos] = (unsigned)src[e] | ((unsigned)etype[e] << 16);
    }
}

// ---------------------------------------------------------------------------
// Fused aggregation + BN + ReLU. One wave per node; lane owns cols (2l,2l+1).
//   out[n] = BN( norm * sum_e T[src_e, et_e*128 ..] + T[n, self] ), ReLU
// 8-way unrolled gather (8 independent accumulator pairs).
// ---------------------------------------------------------------------------
__global__ __launch_bounds__(256) void agg_fused_kernel(
    const unsigned* __restrict__ T32, const int* __restrict__ row_ptr,
    const unsigned* __restrict__ packed, const float* __restrict__ node_norm,
    const float* __restrict__ bn_gamma, const float* __restrict__ bn_beta,
    const float* __restrict__ bn_mean, const float* __restrict__ bn_var,
    void* __restrict__ outp, int out_fp32)
{
    int wave = threadIdx.x >> 6;
    int lane = threadIdx.x & 63;
    int n = blockIdx.x * 4 + wave;
    if (n >= NN) return;
    int s = row_ptr[n];
    int e = row_ptr[n + 1];
    float a0[8], a1[8];
    #pragma unroll
    for (int k = 0; k < 8; k++) { a0[k] = 0.f; a1[k] = 0.f; }
    int i = s;
    for (; i + 7 < e; i += 8) {
        unsigned p[8]; unsigned hv[8];
        #pragma unroll
        for (int k = 0; k < 8; k++) p[k] = packed[i + k];
        #pragma unroll
        for (int k = 0; k < 8; k++)
            hv[k] = T32[(size_t)(p[k] & 0xffffu) * TROW + (p[k] >> 16) * 64 + lane];
        #pragma unroll
        for (int k = 0; k < 8; k++) {
            a0[k] += __uint_as_float(hv[k] << 16);
            a1[k] += __uint_as_float(hv[k] & 0xffff0000u);
        }
    }
    for (; i < e; i++) {
        unsigned p0 = packed[i];
        unsigned hv0 = T32[(size_t)(p0 & 0xffffu) * TROW + (p0 >> 16) * 64 + lane];
        a0[0] += __uint_as_float(hv0 << 16);
        a1[0] += __uint_as_float(hv0 & 0xffff0000u);
    }
    float norm = node_norm[n];
    unsigned self = T32[(size_t)n * TROW + RR * 64 + lane];
    float s0v = ((a0[0] + a0[1]) + (a0[2] + a0[3])) + ((a0[4] + a0[5]) + (a0[6] + a0[7]));
    float s1v = ((a1[0] + a1[1]) + (a1[2] + a1[3])) + ((a1[4] + a1[5]) + (a1[6] + a1[7]));
    float x0 = s0v * norm + __uint_as_float(self << 16);
    float x1 = s1v * norm + __uint_as_float(self & 0xffff0000u);
    int d0 = lane * 2, d1 = lane * 2 + 1;
    float s0 = bn_gamma[d0] * rsqrtf(bn_var[d0] + BN_EPS);
    float s1 = bn_gamma[d1] * rsqrtf(bn_var[d1] + BN_EPS);
    x0 = fmaxf(x0 * s0 + bn_beta[d0] - bn_mean[d0] * s0, 0.f);
    x1 = fmaxf(x1 * s1 + bn_beta[d1] - bn_mean[d1] * s1, 0.f);
    if (out_fp32) {
        float2 o; o.x = x0; o.y = x1;
        *(float2*)&((float*)outp)[(size_t)n * Dh + lane * 2] = o;
    } else {
        ((unsigned*)outp)[(size_t)n * 64 + lane] =
            (unsigned)f2bf(x0) | ((unsigned)f2bf(x1) << 16);
    }
}

// ---------------------------------------------------------------------------
extern "C" void kernel_launch(void* const* d_in, const int* in_sizes, int n_in,
                              void* d_out, int out_size, void* d_ws, size_t ws_size,
                              hipStream_t stream)
{
    const float* node_feat = (const float*)d_in[0];
    const float* W_emb     = (const float*)d_in[1];
    const float* b_emb     = (const float*)d_in[2];
    const float* bases     = (const float*)d_in[3];
    const float* w_coe     = (const float*)d_in[4];
    const float* self_loop = (const float*)d_in[5];
    const float* bn_gamma  = (const float*)d_in[6];
    const float* bn_beta   = (const float*)d_in[7];
    const float* bn_mean   = (const float*)d_in[8];
    const float* bn_var    = (const float*)d_in[9];
    const int*   src       = (const int*)d_in[10];
    const int*   dst       = (const int*)d_in[11];
    const int*   etype     = (const int*)d_in[12];

    char* ws = (char*)d_ws;
    size_t off = 0;
    unsigned short* T = (unsigned short*)(ws + off);      off += (size_t)NN * NW * 2;        // 115.2 MB
    unsigned short* h1 = (unsigned short*)(ws + off);     off += (size_t)NN * Dh * 2;        // 12.8 MB
    unsigned short* nf_bf = (unsigned short*)(ws + off);  off += (size_t)NN * Dh * 2;        // 12.8 MB
    unsigned short* WF0T = (unsigned short*)(ws + off);   off += (size_t)NW * Dh * 2;
    unsigned short* wcatT1 = (unsigned short*)(ws + off); off += (size_t)NW * Dh * 2;
    float* bf0 = (float*)(ws + off);                      off += (size_t)NW * 4;
    float* node_norm = (float*)(ws + off);                off += (size_t)NN * 4;
    int* counts = (int*)(ws + off);                       off += (size_t)NR * 4;             // 1.6 MB
    int* row_ptr = (int*)(ws + off);                      off += ((size_t)NN + 4) * 4;
    int* cursor = (int*)(ws + off);                       off += (size_t)NN * 4;
    int* bsum = (int*)(ws + off);                         off += 256 * 4;
    int* boffset = (int*)(ws + off);                      off += 257 * 4;
    unsigned* packed = (unsigned*)(ws + off);             off += (size_t)EE * 4;             // 3.2 MB

    const int edge_blocks = (EE + 255) / 256;        // 3125
    const int node_blocks = (NN + 255) / 256;        // 196
    dim3 gemm_grid(NW / 64, (NN + 127) / 128);       // 18 x 391 (col fast: A reuse)

    // one-shot prep: weights, folding, input cast, counts zero
    prep_all_kernel<<<PB_ZERO, 256, 0, stream>>>(bases, w_coe, self_loop, W_emb,
                                                 b_emb, node_feat,
                                                 WF0T, wcatT1, bf0, nf_bf, counts);

    // graph structure
    count_kernel<<<edge_blocks, 256, 0, stream>>>(dst, etype, counts);
    scan1_kernel<<<node_blocks, 256, 0, stream>>>(counts, node_norm, row_ptr, bsum);
    scan2_kernel<<<1, 256, 0, stream>>>(bsum, boffset);
    scan3_kernel<<<node_blocks, 256, 0, stream>>>(row_ptr, cursor, boffset);
    fill_kernel<<<edge_blocks, 256, 0, stream>>>(src, dst, etype, cursor, packed);

    // layer 0: T0 = nf @ (W_emb . Wwide0) + b_emb . Wwide0  (embed folded in)
    gemm_wide_kernel<<<gemm_grid, 256, 0, stream>>>(nf_bf, WF0T, bf0, T, NN);
    agg_fused_kernel<<<(NN + 3) / 4, 256, 0, stream>>>((const unsigned*)T, row_ptr, packed,
                                                       node_norm,
                                                       bn_gamma, bn_beta, bn_mean, bn_var,
                                                       h1, 0);
    // layer 1: T1 = h1 @ Wwide1, then fused agg -> d_out (fp32)
    gemm_wide_kernel<<<gemm_grid, 256, 0, stream>>>(h1, wcatT1, nullptr, T, NN);
    agg_fused_kernel<<<(NN + 3) / 4, 256, 0, stream>>>((const unsigned*)T, row_ptr, packed,
                                                       node_norm,
                                                       bn_gamma + Dh, bn_beta + Dh,
                                                       bn_mean + Dh, bn_var + Dh,
                                                       d_out, 1);
}